// Round 1
// baseline (90.170 us; speedup 1.0000x reference)
//
#include <hip/hip_runtime.h>
#include <hip/hip_bf16.h>

// DiversityLoss: reference collapses to
//   out = (||colsum||^2 - B * sum(x^2)) / (D * B * (B-1))
// B=64, D=3*256*256=196608. Single memory-bound pass over 50.3 MB fp32.

__global__ __launch_bounds__(64) void div_zero_ws(float* __restrict__ acc) {
    acc[0] = 0.0f;
}

// One thread per float4 column group; loops over all B=64 rows.
// grid = D4/64 blocks of 64 threads (1 wave per block).
__global__ __launch_bounds__(64) void div_main(const float4* __restrict__ x4,
                                               float* __restrict__ acc,
                                               int D4, int B) {
    const int c = blockIdx.x * 64 + threadIdx.x;
    const float4* p = x4 + c;

    float sx = 0.f, sy = 0.f, sz = 0.f, sw = 0.f;  // column sums
    float sq = 0.f;                                 // sum of squares

    // 64 independent 16B loads, stride D4 float4s apart -> deep MLP,
    // each wave instruction covers 1 KB contiguous.
    #pragma unroll
    for (int r = 0; r < 64; ++r) {
        float4 v = p[(size_t)r * (size_t)D4];
        sx += v.x; sy += v.y; sz += v.z; sw += v.w;
        sq = fmaf(v.x, v.x, sq);
        sq = fmaf(v.y, v.y, sq);
        sq = fmaf(v.z, v.z, sq);
        sq = fmaf(v.w, v.w, sq);
    }

    float contrib = sx * sx + sy * sy + sz * sz + sw * sw - (float)B * sq;

    // wave-64 reduction
    #pragma unroll
    for (int off = 32; off > 0; off >>= 1)
        contrib += __shfl_down(contrib, off, 64);

    if (threadIdx.x == 0)
        atomicAdd(acc, contrib);   // device-scope by default on CDNA
}

__global__ __launch_bounds__(64) void div_finalize(const float* __restrict__ acc,
                                                   float* __restrict__ out,
                                                   float scale) {
    out[0] = acc[0] * scale;
}

extern "C" void kernel_launch(void* const* d_in, const int* in_sizes, int n_in,
                              void* d_out, int out_size, void* d_ws, size_t ws_size,
                              hipStream_t stream) {
    const float* x = (const float*)d_in[0];
    float* out = (float*)d_out;
    float* acc = (float*)d_ws;

    const int B = 64;
    const int total = in_sizes[0];          // 12,582,912
    const int D = total / B;                // 196,608
    const int D4 = D / 4;                   // 49,152
    const int grid = D4 / 64;               // 768 blocks x 64 threads

    // out = reduced / (D * B * (B-1))
    const float scale = (float)(1.0 / ((double)D * (double)B * (double)(B - 1)));

    div_zero_ws<<<1, 64, 0, stream>>>(acc);
    div_main<<<grid, 64, 0, stream>>>((const float4*)x, acc, D4, B);
    div_finalize<<<1, 64, 0, stream>>>(acc, out, scale);
}

// Round 2
// 80.430 us; speedup vs baseline: 1.1211x; 1.1211x over previous
//
#include <hip/hip_runtime.h>
#include <hip/hip_bf16.h>

// DiversityLoss: reference collapses to
//   out = (||colsum||^2 - B * sum(x^2)) / (D * B * (B-1))
// B=64, D=3*256*256=196608. Single memory-bound pass over 50.3 MB fp32.
//
// Round 1 -> 2: occupancy was 3 waves/CU (768 waves, 1 thread/column over
// all 64 rows). Now: 256-thread blocks, 4 row-groups x 16 rows, LDS combine
// of partial column sums -> 3072 waves (12/CU). Deterministic per-block
// partial slots in ws kill both the zero-init kernel and all atomics.

#define NBLK 768   // = D4 / 64 column-tiles

__global__ __launch_bounds__(256) void div_main(const float4* __restrict__ x4,
                                                float* __restrict__ partial,
                                                int D4) {
    const int lane = threadIdx.x & 63;          // float4-column within tile
    const int rg   = threadIdx.x >> 6;          // row-group 0..3 (16 rows each)
    const int col  = blockIdx.x * 64 + lane;

    const float4* p = x4 + (size_t)rg * 16 * (size_t)D4 + col;

    float sx = 0.f, sy = 0.f, sz = 0.f, sw = 0.f;
    float sq = 0.f;

    #pragma unroll
    for (int r = 0; r < 16; ++r) {
        float4 v = p[(size_t)r * (size_t)D4];
        sx += v.x; sy += v.y; sz += v.z; sw += v.w;
        sq = fmaf(v.x, v.x, sq);
        sq = fmaf(v.y, v.y, sq);
        sq = fmaf(v.z, v.z, sq);
        sq = fmaf(v.w, v.w, sq);
    }

    // Every thread contributes -B * sum(x^2) for its chunk.
    float contrib = -64.0f * sq;

    // Combine partial column sums across the 4 row-groups, square on rg 0.
    __shared__ float4 part[3][64];
    if (rg > 0) part[rg - 1][lane] = make_float4(sx, sy, sz, sw);
    __syncthreads();
    if (rg == 0) {
        #pragma unroll
        for (int g = 0; g < 3; ++g) {
            float4 t = part[g][lane];
            sx += t.x; sy += t.y; sz += t.z; sw += t.w;
        }
        contrib += sx * sx + sy * sy + sz * sz + sw * sw;
    }

    // Block reduction: wave-64 shuffle, then 4 wave results via LDS.
    #pragma unroll
    for (int off = 32; off > 0; off >>= 1)
        contrib += __shfl_down(contrib, off, 64);

    __shared__ float wsum[4];
    if (lane == 0) wsum[rg] = contrib;
    __syncthreads();
    if (threadIdx.x == 0)
        partial[blockIdx.x] = wsum[0] + wsum[1] + wsum[2] + wsum[3];
}

__global__ __launch_bounds__(256) void div_finalize(const float* __restrict__ partial,
                                                    float* __restrict__ out,
                                                    float scale) {
    const int t = threadIdx.x;
    float v = partial[t] + partial[t + 256] + partial[t + 512];

    #pragma unroll
    for (int off = 32; off > 0; off >>= 1)
        v += __shfl_down(v, off, 64);

    __shared__ float wsum[4];
    if ((t & 63) == 0) wsum[t >> 6] = v;
    __syncthreads();
    if (t == 0)
        out[0] = (wsum[0] + wsum[1] + wsum[2] + wsum[3]) * scale;
}

extern "C" void kernel_launch(void* const* d_in, const int* in_sizes, int n_in,
                              void* d_out, int out_size, void* d_ws, size_t ws_size,
                              hipStream_t stream) {
    const float* x = (const float*)d_in[0];
    float* out = (float*)d_out;
    float* partial = (float*)d_ws;

    const int B = 64;
    const int total = in_sizes[0];          // 12,582,912
    const int D = total / B;                // 196,608
    const int D4 = D / 4;                   // 49,152

    const float scale = (float)(1.0 / ((double)D * (double)B * (double)(B - 1)));

    div_main<<<NBLK, 256, 0, stream>>>((const float4*)x, partial, D4);
    div_finalize<<<1, 256, 0, stream>>>(partial, out, scale);
}